// Round 8
// baseline (3513.694 us; speedup 1.0000x reference)
//
#include <hip/hip_runtime.h>
#include <stdint.h>

// ---------------------------------------------------------------------------
// Fused SDE sampler, round 10: TWO INDEPENDENT 256-THREAD BLOCKS PER CU.
//   Round-9 crash was a grid bug (4096 tiles/sample vs 2048); and its
//   premise was wrong: weights-in-regs waves need ~250 unified regs ->
//   2 waves/SIMD is intrinsic.  This round keeps 8 waves/CU but splits them
//   into two INDEPENDENT blocks (4 waves, 32 rows each) so one block's
//   barrier drain is filled by the other block's issue stream (round 7
//   showed intra-block ILP cannot fill it).
//   - wave owns 64 neurons: wL1x 32 + wL2 128 regs; W3 -> block LDS (32 KB)
//   - LDS 71.3 KB/block -> 2 blocks/CU (142.6 <= 160); regs ~250 <= 256
//   - all fragment layouts / RNG indices identical to verified round 6
//     (same global element ids -> bit-identical draws)
//   - x0-hoist (pre in 16 regs), per-step scalar table, sqrt2-folded erfinv
// ---------------------------------------------------------------------------

#define PARTITIONABLE 1

namespace {

constexpr int   kObs    = 65536;
constexpr int   kDim    = 64;
constexpr int   kSteps  = 64;
constexpr float kDs     = 1.0f / 64.0f;
constexpr float kSqrtDs = 0.125f;

constexpr int kW3Off   = 192 * 1024;              // 32 W3 tiles (shared)
constexpr int kKeysOff = 224 * 1024;              // uint32[2][64][2] = 1 KB
constexpr int kStabOff = kKeysOff + 1024;         // f32x4[64]        = 1 KB

typedef _Float16 f16x8 __attribute__((ext_vector_type(8)));
typedef _Float16 f16x4 __attribute__((ext_vector_type(4)));
typedef float    f32x4 __attribute__((ext_vector_type(4)));

#define MFMA16(a, b, c) __builtin_amdgcn_mfma_f32_16x16x32_f16((a), (b), (c), 0, 0, 0)

__device__ __forceinline__ uint32_t rotl(uint32_t v, int r) {
  return (v << r) | (v >> (32 - r));
}

__device__ __forceinline__ void tf2x32(uint32_t k0, uint32_t k1,
                                       uint32_t& x0, uint32_t& x1) {
  uint32_t k2 = k0 ^ k1 ^ 0x1BD11BDAu;
  x0 += k0; x1 += k1;
  x0 += x1; x1 = rotl(x1, 13); x1 ^= x0;
  x0 += x1; x1 = rotl(x1, 15); x1 ^= x0;
  x0 += x1; x1 = rotl(x1, 26); x1 ^= x0;
  x0 += x1; x1 = rotl(x1,  6); x1 ^= x0;
  x0 += k1; x1 += k2 + 1u;
  x0 += x1; x1 = rotl(x1, 17); x1 ^= x0;
  x0 += x1; x1 = rotl(x1, 29); x1 ^= x0;
  x0 += x1; x1 = rotl(x1, 16); x1 ^= x0;
  x0 += x1; x1 = rotl(x1, 24); x1 ^= x0;
  x0 += k2; x1 += k0 + 2u;
  x0 += x1; x1 = rotl(x1, 13); x1 ^= x0;
  x0 += x1; x1 = rotl(x1, 15); x1 ^= x0;
  x0 += x1; x1 = rotl(x1, 26); x1 ^= x0;
  x0 += x1; x1 = rotl(x1,  6); x1 ^= x0;
  x0 += k0; x1 += k1 + 3u;
  x0 += x1; x1 = rotl(x1, 17); x1 ^= x0;
  x0 += x1; x1 = rotl(x1, 29); x1 ^= x0;
  x0 += x1; x1 = rotl(x1, 16); x1 ^= x0;
  x0 += x1; x1 = rotl(x1, 24); x1 ^= x0;
  x0 += k1; x1 += k2 + 4u;
  x0 += x1; x1 = rotl(x1, 13); x1 ^= x0;
  x0 += x1; x1 = rotl(x1, 15); x1 ^= x0;
  x0 += x1; x1 = rotl(x1, 26); x1 ^= x0;
  x0 += x1; x1 = rotl(x1,  6); x1 ^= x0;
  x0 += k2; x1 += k0 + 5u;
}

__device__ __forceinline__ void jax_split(uint32_t k0, uint32_t k1,
                                          uint32_t& a0, uint32_t& a1,
                                          uint32_t& b0, uint32_t& b1) {
#if PARTITIONABLE
  uint32_t x0 = 0u, x1 = 0u; tf2x32(k0, k1, x0, x1); a0 = x0; a1 = x1;
  uint32_t y0 = 0u, y1 = 1u; tf2x32(k0, k1, y0, y1); b0 = y0; b1 = y1;
#else
  uint32_t x0 = 0u, x1 = 2u; tf2x32(k0, k1, x0, x1);
  uint32_t y0 = 1u, y1 = 3u; tf2x32(k0, k1, y0, y1);
  a0 = x0; a1 = y0; b0 = x1; b1 = y1;
#endif
}

__device__ __forceinline__ uint32_t draw_bits(uint32_t k0, uint32_t k1, uint32_t i) {
#if PARTITIONABLE
  uint32_t x0 = 0u, x1 = i;
  tf2x32(k0, k1, x0, x1);
  return x0 ^ x1;
#else
  const uint32_t half = (uint32_t)kObs * kDim / 2;
  if (i < half) {
    uint32_t x0 = i, x1 = i + half; tf2x32(k0, k1, x0, x1); return x0;
  } else {
    uint32_t x0 = i - half, x1 = i; tf2x32(k0, k1, x0, x1); return x1;
  }
#endif
}

// returns sqrt(2)*erfinv(x): sqrt(2) folded into the polynomial coefficients
__device__ __forceinline__ float erfinv32s(float x) {
  float w = -__logf(fmaf(-x, x, 1.0f));
  float p;
  if (w < 5.0f) {
    w = w - 2.5f;
    p =            3.974239e-08f;
    p = fmaf(p, w, 4.854653e-07f);
    p = fmaf(p, w, -4.982823e-06f);
    p = fmaf(p, w, -6.210533e-06f);
    p = fmaf(p, w, 3.091202e-04f);
    p = fmaf(p, w, -1.773035e-03f);
    p = fmaf(p, w, -5.908134e-03f);
    p = fmaf(p, w, 3.488027e-01f);
    p = fmaf(p, w, 2.1233135f);
  } else {
    w = sqrtf(w) - 3.0f;
    p =            -2.8314694e-04f;
    p = fmaf(p, w, 1.4276561e-04f);
    p = fmaf(p, w, 1.908261e-03f);
    p = fmaf(p, w, -5.1950111e-03f);
    p = fmaf(p, w, 8.1168903e-03f);
    p = fmaf(p, w, -1.07797888e-02f);
    p = fmaf(p, w, 1.33485780e-02f);
    p = fmaf(p, w, 1.4165811f);
    p = fmaf(p, w, 4.0064343f);
  }
  return p * x;
}

__device__ __forceinline__ float bits_to_normal(uint32_t bits) {
  const float lo = -0.99999994f;
  float f = __uint_as_float(0x3f800000u | (bits >> 9)) - 1.0f;
  float u = fmaxf(lo, fmaf(f, 2.0f, lo));
  return erfinv32s(u);
}

}  // namespace

// ---------------------------------------------------------------------------
// Weight prep for the 4-wave partition.
// Tile = 16(M) x 32(K), 1024 B; lane l holds W[k=(l>>4)*8+j][m=l&15].
// Per-wave region (48 KB, w in [0,4)), tile T:
//   T in [ 0, 8) : L1x  mt=T>>1, kt=T&1   (W1 rows 0..63, cols w*64+mt*16+..)
//   T in [ 8,16) : L1x0 mt=(T-8)>>1, kt=(T-8)&1  (W1 rows 64..127)
//   T in [16,48) : L2   u=T-16, mt=u>>3, kt=u&7
// Shared W3 region @192KB: u in [0,32): mt=u>>3 (dim-tile), kt=u&7.
// Block 224: keys + step scalars.
// ---------------------------------------------------------------------------
__global__ void prep_weights(const float* __restrict__ W1,
                             const float* __restrict__ W2,
                             const float* __restrict__ W3,
                             _Float16* __restrict__ ws) {
  const int G = blockIdx.x;
  const int t = threadIdx.x;

  if (G >= 224) {
    if (t < 2) {
      uint32_t* kout = (uint32_t*)((char*)ws + kKeysOff) + t * 128;
      uint32_t s0a, s0b, s1a, s1b;
      jax_split(0u, 1u, s0a, s0b, s1a, s1b);
      const uint32_t sk0 = t ? s1a : s0a;
      const uint32_t sk1 = t ? s1b : s0b;
      uint32_t kd0, kd1, kl0, kl1;
      jax_split(sk0, sk1, kd0, kd1, kl0, kl1);
      kout[0] = kd0; kout[1] = kd1;
      for (int n = 1; n < kSteps; ++n) {
        uint32_t na, nb, xa, xb;
        jax_split(kl0, kl1, na, nb, xa, xb);
        kl0 = na; kl1 = nb;
        kout[2 * n] = xa; kout[2 * n + 1] = xb;
      }
    }
    if (t < kSteps) {
      const float s  = (float)t * kDs;
      const float sg = 1.0f - s;
      f32x4 v;
      v[0] = s;
      v[1] = (t == 0) ? 0.0f : 1.0f / (s * sg);
      v[2] = 0.5f * (1.0f - sg * sg);
      v[3] = kDs * v[2] * v[1];                    // P = ds*coef*A
      *(f32x4*)((char*)ws + kStabOff + t * 16) = v;
    }
    return;
  }

  const int lane = t >> 2;
  const int j0   = (t & 3) * 2;
  const int lm   = lane & 15;
  const int kb   = (lane >> 4) << 3;

#pragma unroll
  for (int jj = 0; jj < 2; ++jj) {
    const int j = j0 + jj;
    float v;
    if (G < 192) {
      const int w = G / 48;
      const int T = G % 48;
      if (T < 8) {
        const int mt = T >> 1, kt = T & 1;
        const int col = w * 64 + mt * 16 + lm;
        const int k   = kt * 32 + kb + j;          // W1 x-rows 0..63
        v = W1[k * 256 + col];
      } else if (T < 16) {
        const int u = T - 8;
        const int mt = u >> 1, kt = u & 1;
        const int col = w * 64 + mt * 16 + lm;
        const int k   = 64 + kt * 32 + kb + j;     // W1 x0-rows 64..127
        v = W1[k * 256 + col];
      } else {
        const int u = T - 16;
        const int mt = u >> 3, kt = u & 7;
        const int col = w * 64 + mt * 16 + lm;
        const int k   = kt * 32 + kb + j;
        v = W2[k * 256 + col];
      }
    } else {
      const int u  = G - 192;
      const int mt = u >> 3, kt = u & 7;
      const int col = mt * 16 + lm;
      const int k   = kt * 32 + kb + j;
      v = W3[k * 64 + col];
    }
    ws[(size_t)G * 512 + lane * 8 + j] = (_Float16)v;
  }
}

// ---------------------------------------------------------------------------
// Main fused kernel: 256 threads / 4 waves / 32 rows; 2 blocks per CU.
// ---------------------------------------------------------------------------
__global__ __launch_bounds__(256, 2)
void sde_mfma(const float* __restrict__ X0g,
              const float* __restrict__ W1,
              const float* __restrict__ b1,
              const float* __restrict__ b2,
              const float* __restrict__ b3,
              const _Float16* __restrict__ ws,
              float* __restrict__ out) {
  // Fragment-tile LDS: 1 KB tiles; elem (k,n) -> slot ((k&31)>>3)*16+(n&15),
  // byte slot*16+(k&7)*2.  Tile id = ktile*2 + rowtile (rows: 2 tiles of 16).
  // Total = 4 + 16 + 16 + 32 + 3.3 = 71.3 KB -> 2 blocks/CU.
  __shared__ alignas(16) char  xAf [4 * 1024];    // x state   (dim-kt 2 x rt 2)
  __shared__ alignas(16) char  h1f [16 * 1024];   // h1 (kt 8 x rt 2); x0-scratch
  __shared__ alignas(16) char  h2f [16 * 1024];
  __shared__ alignas(16) char  w3f [32 * 1024];   // W3 A-fragments (shared)
  __shared__ alignas(16) float bb  [832];         // b1|W1s|b2 (256 ea) | b3(64)

  const int t    = threadIdx.x;
  const int w    = t >> 6;                 // wave 0..3: neurons [64w, 64w+64)
  const int l    = t & 63;
  const int lq   = l >> 4;
  const int lm   = l & 15;
  const int samp = blockIdx.x >> 11;       // 2048 blocks per sample
  const int tile = blockIdx.x & 2047;
  const int r0   = tile * 32;
  const int d0   = w * 16 + lq * 4;        // L3: wave w owns dims [16w,16w+16)

  const int rb  = l * 16;                                    // consumer read
  const int lo1 = ((lq >> 1) * 16 + lm) * 16 + (lq & 1) * 8; // producer sub-off
  const int ln3 = (((w & 1) * 2 + (lq >> 1)) * 16 + lm) * 16 + (lq & 1) * 8;

  // ---- stage biases + s-row of W1 ----
  bb[t]       = b1[t];
  bb[256 + t] = W1[128 * 256 + t];
  bb[512 + t] = b2[t];
  if (t < 64) bb[768 + t] = b3[t];

  // ---- stage X0 into fragment layout: xAf (live) + h1f (hoist scratch) ----
  {
    const int li = t >> 3;                 // row 0..31
    const int ci = (t & 7) * 8;            // dim base
    const float* p = X0g + (size_t)(r0 + li) * kDim + ci;
    const float4 a = *(const float4*)p;
    const float4 b = *(const float4*)(p + 4);
    f16x8 h;
    h[0] = (_Float16)a.x; h[1] = (_Float16)a.y;
    h[2] = (_Float16)a.z; h[3] = (_Float16)a.w;
    h[4] = (_Float16)b.x; h[5] = (_Float16)b.y;
    h[6] = (_Float16)b.z; h[7] = (_Float16)b.w;
    const int fa = ((ci >> 5) * 2 + (li >> 4)) * 1024 +
                   (((ci >> 3) & 3) * 16 + (li & 15)) * 16;
    *(f16x8*)(xAf + fa) = h;
    *(f16x8*)(h1f + fa) = h;
  }

  // ---- stage W3 fragments into LDS (32 KB, shared by all 4 waves) ----
#pragma unroll
  for (int j = 0; j < 8; ++j)
    *(f16x8*)(w3f + j * 4096 + t * 16) =
        *(const f16x8*)((const char*)ws + kW3Off + j * 4096 + t * 16);

  // ---- own state: rows rt*16+lm, dims d0..d0+3 ----
  float xv[2][4];
  f32x4 x0q[2];
#pragma unroll
  for (int rt = 0; rt < 2; ++rt) {
    const int row = rt * 16 + lm;
    x0q[rt] = *(const f32x4*)(X0g + (size_t)(r0 + row) * kDim + d0);
#pragma unroll
    for (int q = 0; q < 4; ++q) xv[rt][q] = x0q[rt][q];
  }
  const uint32_t giA = (uint32_t)((r0 + lm) * kDim + d0);
  const uint32_t giB = giA + 16u * kDim;

  // ---- preload persistent weights: L1x (32 regs) + L2 (128 regs) ----
  const char* pW = (const char*)ws + (size_t)w * 48 * 1024 + l * 16;
  f16x8 wL1[4][2], wL2[32];
#pragma unroll
  for (int mt = 0; mt < 4; ++mt) {
    wL1[mt][0] = *(const f16x8*)(pW + (mt * 2 + 0) * 1024);
    wL1[mt][1] = *(const f16x8*)(pW + (mt * 2 + 1) * 1024);
  }
#pragma unroll
  for (int i = 0; i < 32; ++i)
    wL2[i] = *(const f16x8*)(pW + (16 + i) * 1024);

  const uint32_t* keys = (const uint32_t*)((const char*)ws + kKeysOff) + samp * 128;
  const f32x4*    stab = (const f32x4*)((const char*)ws + kStabOff);

  __syncthreads();

  // ---- hoist: pre[rt][mt] = W1[x0 rows]·x0 (step-invariant; wx0 transient) ----
  f16x4 pre[2][4];
  {
    f16x8 wx0[4][2];
#pragma unroll
    for (int mt = 0; mt < 4; ++mt) {
      wx0[mt][0] = *(const f16x8*)(pW + (8 + mt * 2 + 0) * 1024);
      wx0[mt][1] = *(const f16x8*)(pW + (8 + mt * 2 + 1) * 1024);
    }
#pragma unroll
    for (int rt = 0; rt < 2; ++rt) {
      const f16x8 xf0 = *(const f16x8*)(h1f + (0 * 2 + rt) * 1024 + rb);
      const f16x8 xf1 = *(const f16x8*)(h1f + (1 * 2 + rt) * 1024 + rb);
#pragma unroll
      for (int mt = 0; mt < 4; ++mt) {
        f32x4 p = {0.f, 0.f, 0.f, 0.f};
        p = MFMA16(wx0[mt][0], xf0, p);
        p = MFMA16(wx0[mt][1], xf1, p);
        f16x4 ph;
#pragma unroll
        for (int q = 0; q < 4; ++q) ph[q] = (_Float16)p[q];
        pre[rt][mt] = ph;
      }
    }
  }
  __syncthreads();   // scratch reads done before L1 overwrites h1f

  for (int n = 0; n < kSteps; ++n) {
    const f32x4 st = stab[n];
    const float s = st[0], P = st[3];
    const uint32_t ka = keys[2 * n], kbk = keys[2 * n + 1];

    // ---- eta for rt=0 (fills L1's MFMA waits) ----
    float et0[4];
#pragma unroll
    for (int q = 0; q < 4; ++q)
      et0[q] = bits_to_normal(draw_bits(ka, kbk, giA + q));

    // ========== layer 1: M=64 (wave's neurons), N=32, K=64 (x only) ======
#pragma unroll
    for (int rt = 0; rt < 2; ++rt) {
      const f16x8 bf0 = *(const f16x8*)(xAf + (0 * 2 + rt) * 1024 + rb);
      const f16x8 bf1 = *(const f16x8*)(xAf + (1 * 2 + rt) * 1024 + rb);
#pragma unroll
      for (int mt = 0; mt < 4; ++mt) {
        f32x4 c = {0.f, 0.f, 0.f, 0.f};
        c = MFMA16(wL1[mt][0], bf0, c);
        c = MFMA16(wL1[mt][1], bf1, c);
        const int nb = w * 64 + mt * 16 + lq * 4;
        const f32x4 bq = *(const f32x4*)&bb[nb];
        const f32x4 wq = *(const f32x4*)&bb[256 + nb];
        const f16x4 ph = pre[rt][mt];
        f16x4 o;
#pragma unroll
        for (int q = 0; q < 4; ++q)
          o[q] = (_Float16)fmaxf(c[q] + (float)ph[q] + fmaf(s, wq[q], bq[q]), 0.f);
        *(f16x4*)(h1f + ((w * 2 + (mt >> 1)) * 2 + rt) * 1024 +
                  (mt & 1) * 512 + lo1) = o;
      }
    }
    __syncthreads();

    // ========== layer 2: M=64, N=32, K=256 (+ eta rt=1 between halves) ====
    float et1[4];
#pragma unroll
    for (int rt = 0; rt < 2; ++rt) {
      f32x4 c[4];
#pragma unroll
      for (int mt = 0; mt < 4; ++mt) c[mt] = (f32x4){0.f, 0.f, 0.f, 0.f};
#pragma unroll
      for (int kh = 0; kh < 2; ++kh) {
        f16x8 bh[4];
#pragma unroll
        for (int k4 = 0; k4 < 4; ++k4)
          bh[k4] = *(const f16x8*)
              (h1f + ((kh * 4 + k4) * 2 + rt) * 1024 + rb);
#pragma unroll
        for (int k4 = 0; k4 < 4; ++k4)
#pragma unroll
          for (int mt = 0; mt < 4; ++mt)
            c[mt] = MFMA16(wL2[mt * 8 + kh * 4 + k4], bh[k4], c[mt]);
      }
      if (rt == 0) {
#pragma unroll
        for (int q = 0; q < 4; ++q)
          et1[q] = bits_to_normal(draw_bits(ka, kbk, giB + q));
      }
#pragma unroll
      for (int mt = 0; mt < 4; ++mt) {
        const int nb = w * 64 + mt * 16 + lq * 4;
        const f32x4 bq = *(const f32x4*)&bb[512 + nb];
        f16x4 o;
#pragma unroll
        for (int q = 0; q < 4; ++q)
          o[q] = (_Float16)fmaxf(c[mt][q] + bq[q], 0.f);
        *(f16x4*)(h2f + ((w * 2 + (mt >> 1)) * 2 + rt) * 1024 +
                  (mt & 1) * 512 + lo1) = o;
      }
    }
    __syncthreads();

    // ========== layer 3 (dims [16w,16w+16), W3 from LDS) + update ==========
    const f32x4 b3q = *(const f32x4*)&bb[768 + d0];
#pragma unroll
    for (int rt = 0; rt < 2; ++rt) {
      f32x4 dA = {0.f, 0.f, 0.f, 0.f}, dB = {0.f, 0.f, 0.f, 0.f};
#pragma unroll
      for (int kh = 0; kh < 2; ++kh) {
        f16x8 bh[4], wf[4];
#pragma unroll
        for (int k4 = 0; k4 < 4; ++k4) {
          bh[k4] = *(const f16x8*)
              (h2f + ((kh * 4 + k4) * 2 + rt) * 1024 + rb);
          wf[k4] = *(const f16x8*)
              (w3f + (w * 8 + kh * 4 + k4) * 1024 + rb);
        }
        dA = MFMA16(wf[0], bh[0], dA);
        dB = MFMA16(wf[1], bh[1], dB);
        dA = MFMA16(wf[2], bh[2], dA);
        dB = MFMA16(wf[3], bh[3], dB);
      }
      f16x4 hx;
#pragma unroll
      for (int q = 0; q < 4; ++q) {
        const float ov  = dA[q] + dB[q] + b3q[q];
        const float eta = rt ? et1[q] : et0[q];
        // nx = xv + ds*ov + P*(s*ov - xv + x0q) + sqrt(ds)*eta
        const float t1  = fmaf(s, ov, x0q[rt][q] - xv[rt][q]);
        float nx = fmaf(kSqrtDs, eta, xv[rt][q]);
        nx = fmaf(kDs, ov, nx);
        nx = fmaf(P, t1, nx);
        xv[rt][q] = nx;
        hx[q] = (_Float16)nx;
      }
      *(f16x4*)(xAf + ((w >> 1) * 2 + rt) * 1024 + ln3) = hx;
    }
    __syncthreads();
  }

  // ---- write result (each lane owns its 8 elements) ----
#pragma unroll
  for (int rt = 0; rt < 2; ++rt) {
    const int row = rt * 16 + lm;
    const size_t ob = (size_t)samp * ((size_t)kObs * kDim) +
                      (size_t)(r0 + row) * kDim + d0;
    f32x4 v;
#pragma unroll
    for (int q = 0; q < 4; ++q) v[q] = xv[rt][q];
    *(f32x4*)(out + ob) = v;
  }
}

extern "C" void kernel_launch(void* const* d_in, const int* in_sizes, int n_in,
                              void* d_out, int out_size, void* d_ws, size_t ws_size,
                              hipStream_t stream) {
  const float* X0 = (const float*)d_in[0];
  const float* W1 = (const float*)d_in[1];
  const float* b1 = (const float*)d_in[2];
  const float* W2 = (const float*)d_in[3];
  const float* b2 = (const float*)d_in[4];
  const float* W3 = (const float*)d_in[5];
  const float* b3 = (const float*)d_in[6];
  _Float16* ws = (_Float16*)d_ws;   // 224 KB fragments + 2 KB key/scalar tables

  prep_weights<<<dim3(225), dim3(256), 0, stream>>>(W1, W2, W3, ws);
  sde_mfma<<<dim3(4096), dim3(256), 0, stream>>>(X0, W1, b1, b2, b3, ws,
                                                 (float*)d_out);
}

// Round 9
// 2803.778 us; speedup vs baseline: 1.2532x; 1.2532x over previous
//
#include <hip/hip_runtime.h>
#include <stdint.h>

// ---------------------------------------------------------------------------
// Fused SDE sampler, round 11: REVERT TO VERIFIED ROUND-6 OPTIMUM (2793 us).
//   R7 (phase interleave): neutral.  R8 (+28 bias regs): spilled.  R9: grid
//   bug.  R10 (+48 weight regs, 2 blocks/CU): spilled (WRITE_SIZE 176 MB).
//   Conclusion: 2 waves/SIMD is intrinsic (weights-in-regs ~250 unified
//   regs); VALU 70% + MFMA ~25% = ~95% combined pipe saturation; VALU is
//   dominated by irreducible bit-exact threefry (8 draws/thread-step).
//   This is the round-6 source verbatim:
//   - x0 half of layer 1 hoisted (step-invariant, pre[4][2] f16)
//   - etas for step n+1 computed inside step n's L2 (issue-slot filling)
//   - P = ds*coef*A per-step scalar table; fragment-linear LDS (conflict-free
//     b128 reads); weights in 112 VGPRs; fused in-register E-M update.
// ---------------------------------------------------------------------------

#define PARTITIONABLE 1

namespace {

constexpr int   kObs    = 65536;
constexpr int   kDim    = 64;
constexpr int   kSteps  = 64;
constexpr float kDs     = 1.0f / 64.0f;
constexpr float kSqrtDs = 0.125f;

constexpr int kWeightBytes = 256 * 1024;          // 8 waves x 32 tiles x 1 KB
constexpr int kKeysOff     = kWeightBytes;        // uint32[2][64][2] = 1 KB
constexpr int kStabOff     = kKeysOff + 1024;     // f32x4[64]        = 1 KB

typedef _Float16 f16x8 __attribute__((ext_vector_type(8)));
typedef _Float16 f16x4 __attribute__((ext_vector_type(4)));
typedef float    f32x4 __attribute__((ext_vector_type(4)));

#define MFMA16(a, b, c) __builtin_amdgcn_mfma_f32_16x16x32_f16((a), (b), (c), 0, 0, 0)

__device__ __forceinline__ uint32_t rotl(uint32_t v, int r) {
  return (v << r) | (v >> (32 - r));
}

__device__ __forceinline__ void tf2x32(uint32_t k0, uint32_t k1,
                                       uint32_t& x0, uint32_t& x1) {
  uint32_t k2 = k0 ^ k1 ^ 0x1BD11BDAu;
  x0 += k0; x1 += k1;
  x0 += x1; x1 = rotl(x1, 13); x1 ^= x0;
  x0 += x1; x1 = rotl(x1, 15); x1 ^= x0;
  x0 += x1; x1 = rotl(x1, 26); x1 ^= x0;
  x0 += x1; x1 = rotl(x1,  6); x1 ^= x0;
  x0 += k1; x1 += k2 + 1u;
  x0 += x1; x1 = rotl(x1, 17); x1 ^= x0;
  x0 += x1; x1 = rotl(x1, 29); x1 ^= x0;
  x0 += x1; x1 = rotl(x1, 16); x1 ^= x0;
  x0 += x1; x1 = rotl(x1, 24); x1 ^= x0;
  x0 += k2; x1 += k0 + 2u;
  x0 += x1; x1 = rotl(x1, 13); x1 ^= x0;
  x0 += x1; x1 = rotl(x1, 15); x1 ^= x0;
  x0 += x1; x1 = rotl(x1, 26); x1 ^= x0;
  x0 += x1; x1 = rotl(x1,  6); x1 ^= x0;
  x0 += k0; x1 += k1 + 3u;
  x0 += x1; x1 = rotl(x1, 17); x1 ^= x0;
  x0 += x1; x1 = rotl(x1, 29); x1 ^= x0;
  x0 += x1; x1 = rotl(x1, 16); x1 ^= x0;
  x0 += x1; x1 = rotl(x1, 24); x1 ^= x0;
  x0 += k1; x1 += k2 + 4u;
  x0 += x1; x1 = rotl(x1, 13); x1 ^= x0;
  x0 += x1; x1 = rotl(x1, 15); x1 ^= x0;
  x0 += x1; x1 = rotl(x1, 26); x1 ^= x0;
  x0 += x1; x1 = rotl(x1,  6); x1 ^= x0;
  x0 += k2; x1 += k0 + 5u;
}

__device__ __forceinline__ void jax_split(uint32_t k0, uint32_t k1,
                                          uint32_t& a0, uint32_t& a1,
                                          uint32_t& b0, uint32_t& b1) {
#if PARTITIONABLE
  uint32_t x0 = 0u, x1 = 0u; tf2x32(k0, k1, x0, x1); a0 = x0; a1 = x1;
  uint32_t y0 = 0u, y1 = 1u; tf2x32(k0, k1, y0, y1); b0 = y0; b1 = y1;
#else
  uint32_t x0 = 0u, x1 = 2u; tf2x32(k0, k1, x0, x1);
  uint32_t y0 = 1u, y1 = 3u; tf2x32(k0, k1, y0, y1);
  a0 = x0; a1 = y0; b0 = x1; b1 = y1;
#endif
}

__device__ __forceinline__ uint32_t draw_bits(uint32_t k0, uint32_t k1, uint32_t i) {
#if PARTITIONABLE
  uint32_t x0 = 0u, x1 = i;
  tf2x32(k0, k1, x0, x1);
  return x0 ^ x1;
#else
  const uint32_t half = (uint32_t)kObs * kDim / 2;
  if (i < half) {
    uint32_t x0 = i, x1 = i + half; tf2x32(k0, k1, x0, x1); return x0;
  } else {
    uint32_t x0 = i - half, x1 = i; tf2x32(k0, k1, x0, x1); return x1;
  }
#endif
}

__device__ __forceinline__ float erfinv32(float x) {
  float w = -__logf(fmaf(-x, x, 1.0f));
  float p;
  if (w < 5.0f) {
    w = w - 2.5f;
    p =            2.81022636e-08f;
    p = fmaf(p, w, 3.43273939e-07f);
    p = fmaf(p, w, -3.5233877e-06f);
    p = fmaf(p, w, -4.39150654e-06f);
    p = fmaf(p, w, 0.00021858087f);
    p = fmaf(p, w, -0.00125372503f);
    p = fmaf(p, w, -0.00417768164f);
    p = fmaf(p, w, 0.246640727f);
    p = fmaf(p, w, 1.50140941f);
  } else {
    w = sqrtf(w) - 3.0f;
    p =            -0.000200214257f;
    p = fmaf(p, w, 0.000100950558f);
    p = fmaf(p, w, 0.00134934322f);
    p = fmaf(p, w, -0.00367342844f);
    p = fmaf(p, w, 0.00573950773f);
    p = fmaf(p, w, -0.0076224613f);
    p = fmaf(p, w, 0.00943887047f);
    p = fmaf(p, w, 1.00167406f);
    p = fmaf(p, w, 2.83297682f);
  }
  return p * x;
}

__device__ __forceinline__ float bits_to_normal(uint32_t bits) {
  const float lo = -0.99999994f;
  float f = __uint_as_float(0x3f800000u | (bits >> 9)) - 1.0f;
  float u = fmaxf(lo, fmaf(f, 2.0f, lo));
  return 1.41421356237f * erfinv32(u);
}

}  // namespace

// ---------------------------------------------------------------------------
// Weight prep: per-wave contiguous fragment tiles + RNG/step tables.
// (fragment packing identical to rounds 4/5 — verified; stab gains P=v[3])
// ---------------------------------------------------------------------------
__global__ void prep_weights(const float* __restrict__ W1,
                             const float* __restrict__ W2,
                             const float* __restrict__ W3,
                             _Float16* __restrict__ ws) {
  const int G = blockIdx.x;
  const int t = threadIdx.x;

  if (G >= 256) {
    if (t < 2) {
      uint32_t* kout = (uint32_t*)((char*)ws + kKeysOff) + t * 128;
      uint32_t s0a, s0b, s1a, s1b;
      jax_split(0u, 1u, s0a, s0b, s1a, s1b);
      const uint32_t sk0 = t ? s1a : s0a;
      const uint32_t sk1 = t ? s1b : s0b;
      uint32_t kd0, kd1, kl0, kl1;
      jax_split(sk0, sk1, kd0, kd1, kl0, kl1);
      kout[0] = kd0; kout[1] = kd1;
      for (int n = 1; n < kSteps; ++n) {
        uint32_t na, nb, xa, xb;
        jax_split(kl0, kl1, na, nb, xa, xb);
        kl0 = na; kl1 = nb;
        kout[2 * n] = xa; kout[2 * n + 1] = xb;
      }
    }
    if (t < kSteps) {
      const float s  = (float)t * kDs;
      const float sg = 1.0f - s;
      f32x4 v;
      v[0] = s;
      v[1] = (t == 0) ? 0.0f : 1.0f / (s * sg);
      v[2] = 0.5f * (1.0f - sg * sg);
      v[3] = kDs * v[2] * v[1];                    // P = ds*coef*A
      *(f32x4*)((char*)ws + kStabOff + t * 16) = v;
    }
    return;
  }

  const int lane = t >> 2;
  const int j0   = (t & 3) * 2;
  const int w    = G >> 5;
  const int T    = G & 31;
  const int lm   = lane & 15;
  const int kb   = (lane >> 4) << 3;

#pragma unroll
  for (int jj = 0; jj < 2; ++jj) {
    const int j = j0 + jj;
    float v;
    if (T < 8) {
      const int mt = T >> 2, kt = T & 3;
      const int col = w * 32 + mt * 16 + lm;
      const int k   = kt * 32 + kb + j;          // 0..127 : [x | x0] rows of W1
      v = W1[k * 256 + col];
    } else if (T < 24) {
      const int u = T - 8;
      const int mt = u >> 3, kt = u & 7;
      const int col = w * 32 + mt * 16 + lm;
      const int k   = kt * 32 + kb + j;
      v = W2[k * 256 + col];
    } else {
      const int kt  = T - 24;
      const int col = (w >> 1) * 16 + lm;        // L3 dim-tile = w>>1
      const int k   = kt * 32 + kb + j;
      v = W3[k * 64 + col];
    }
    ws[(size_t)G * 512 + lane * 8 + j] = (_Float16)v;
  }
}

// ---------------------------------------------------------------------------
// Main fused kernel: register weights, fragment LDS, hoisted x0, piped RNG.
// ---------------------------------------------------------------------------
__global__ __launch_bounds__(512, 2)
void sde_mfma(const float* __restrict__ X0g,
              const float* __restrict__ W1,
              const float* __restrict__ b1,
              const float* __restrict__ b2,
              const float* __restrict__ b3,
              const _Float16* __restrict__ ws,
              float* __restrict__ out) {
  // Fragment-tile LDS: tile(kt,nt) = 1KB; elem (k,n) -> lane'=((k&31)>>3)*16
  // + (n&15), byte lane'*16 + (k&7)*2.  Consumer b128 read = tile + l*16.
  __shared__ alignas(16) char  xAf [8 * 1024];    // kt(2) x nt(4), dims x rows
  __shared__ alignas(16) char  h1f [32 * 1024];   // kt(8) x nt(4); x0-scratch @init
  __shared__ alignas(16) char  h2f [32 * 1024];
  __shared__ alignas(16) float bb  [832];         // b1|W1s|b2 (256 ea) | b3(64)

  const int t    = threadIdx.x;
  const int w    = t >> 6;                 // wave 0..7: neurons [32w,32w+32)
  const int l    = t & 63;
  const int lq   = l >> 4;
  const int lm   = l & 15;
  const int samp = blockIdx.x >> 10;       // 1024 blocks per sample
  const int tile = blockIdx.x & 1023;
  const int r0   = tile * 64;
  const int mt3  = w >> 1;                 // L3 dim-tile
  const int ntb  = (w & 1) * 2;            // L3 row-tile base (2 tiles)
  const int d0   = mt3 * 16 + lq * 4;      // this lane's 4 dims

  const int rb  = l * 16;                                  // consumer read off
  const int lo1 = ((lq >> 1) * 16 + lm) * 16 + (lq & 1) * 8; // producer (mt=0)
  const int kt3 = mt3 >> 1;
  const int ln3 = (((mt3 & 1) * 2 + (lq >> 1)) * 16 + lm) * 16 + (lq & 1) * 8;

  // ---- stage biases + s-row of W1 ----
  if (t < 256) {
    bb[t]       = b1[t];
    bb[256 + t] = W1[128 * 256 + t];
    bb[512 + t] = b2[t];
  } else if (t < 320) {
    bb[768 + (t - 256)] = b3[t - 256];
  }

  // ---- stage X0 into fragment layout: xAf (live) + h1f (hoist scratch) ----
  {
    const int li = t >> 3;                 // row 0..63
    const int ci = (t & 7) * 8;            // dim base
    const float* p = X0g + (size_t)(r0 + li) * kDim + ci;
    const float4 a = *(const float4*)p;
    const float4 b = *(const float4*)(p + 4);
    f16x8 h;
    h[0] = (_Float16)a.x; h[1] = (_Float16)a.y;
    h[2] = (_Float16)a.z; h[3] = (_Float16)a.w;
    h[4] = (_Float16)b.x; h[5] = (_Float16)b.y;
    h[6] = (_Float16)b.z; h[7] = (_Float16)b.w;
    const int fa = ((ci >> 5) * 4 + (li >> 4)) * 1024 +
                   (((ci >> 3) & 3) * 16 + (li & 15)) * 16;
    *(f16x8*)(xAf + fa) = h;
    *(f16x8*)(h1f + fa) = h;               // scratch copy for x0-hoist
  }

  // ---- own state (f32, registers): rows (ntb+ni)*16+lm, dims d0..d0+3 ----
  float xv[2][4];
  f32x4 x0q[2];
#pragma unroll
  for (int ni = 0; ni < 2; ++ni) {
    const int row = (ntb + ni) * 16 + lm;
    x0q[ni] = *(const f32x4*)(X0g + (size_t)(r0 + row) * kDim + d0);
#pragma unroll
    for (int q = 0; q < 4; ++q) xv[ni][q] = x0q[ni][q];
  }
  const uint32_t giA = (uint32_t)((r0 + ntb * 16 + lm) * kDim + d0);
  const uint32_t giB = giA + 16u * kDim;

  // ---- preload weight fragments: L1 x-part (4), L2 (16), L3 (8) = 112 regs;
  //      x0-part (4) transient for the hoist ----
  const char* pW = (const char*)ws + (size_t)w * 32768 + l * 16;
  f16x8 wL1[2][2], wx0[2][2], wL2[16], wL3[8];
#pragma unroll
  for (int mt = 0; mt < 2; ++mt) {
    wL1[mt][0] = *(const f16x8*)(pW + (mt * 4 + 0) * 1024);
    wL1[mt][1] = *(const f16x8*)(pW + (mt * 4 + 1) * 1024);
    wx0[mt][0] = *(const f16x8*)(pW + (mt * 4 + 2) * 1024);
    wx0[mt][1] = *(const f16x8*)(pW + (mt * 4 + 3) * 1024);
  }
#pragma unroll
  for (int i = 0; i < 16; ++i) wL2[i] = *(const f16x8*)(pW + (8 + i) * 1024);
#pragma unroll
  for (int i = 0; i < 8; ++i)  wL3[i] = *(const f16x8*)(pW + (24 + i) * 1024);

  const uint32_t* keys = (const uint32_t*)((const char*)ws + kKeysOff) + samp * 128;
  const f32x4*    stab = (const f32x4*)((const char*)ws + kStabOff);

  __syncthreads();

  // ---- hoist: pre[nt][mt] = W1[x0 rows]·x0  (step-invariant, f16x4) ----
  f16x4 pre[4][2];
#pragma unroll
  for (int nt = 0; nt < 4; ++nt) {
    const f16x8 xf0 = *(const f16x8*)(h1f + (0 * 4 + nt) * 1024 + rb);
    const f16x8 xf1 = *(const f16x8*)(h1f + (1 * 4 + nt) * 1024 + rb);
#pragma unroll
    for (int mt = 0; mt < 2; ++mt) {
      f32x4 p = {0.f, 0.f, 0.f, 0.f};
      p = MFMA16(wx0[mt][0], xf0, p);
      p = MFMA16(wx0[mt][1], xf1, p);
      f16x4 ph;
#pragma unroll
      for (int q = 0; q < 4; ++q) ph[q] = (_Float16)p[q];
      pre[nt][mt] = ph;
    }
  }
  __syncthreads();   // scratch reads done before L1 overwrites h1f

  // ---- RNG pipeline prologue: etas for step 0 ----
  float etaA[4], etaB[4];
  {
    const uint32_t ka = keys[0], kb0 = keys[1];
#pragma unroll
    for (int q = 0; q < 4; ++q) etaA[q] = bits_to_normal(draw_bits(ka, kb0, giA + q));
#pragma unroll
    for (int q = 0; q < 4; ++q) etaB[q] = bits_to_normal(draw_bits(ka, kb0, giB + q));
  }

  for (int n = 0; n < kSteps; ++n) {
    const f32x4 st = stab[n];
    const float s = st[0], P = st[3];
    const int np = (n + 1 < kSteps) ? n + 1 : n;
    const uint32_t kna = keys[2 * np], knb = keys[2 * np + 1];

    // ========== layer 1: M=32 (wave's neurons), N=64, K=64 (x only) ======
#pragma unroll
    for (int nt = 0; nt < 4; ++nt) {
      const f16x8 bf0 = *(const f16x8*)(xAf + (0 * 4 + nt) * 1024 + rb);
      const f16x8 bf1 = *(const f16x8*)(xAf + (1 * 4 + nt) * 1024 + rb);
#pragma unroll
      for (int mt = 0; mt < 2; ++mt) {
        f32x4 c = {0.f, 0.f, 0.f, 0.f};
        c = MFMA16(wL1[mt][0], bf0, c);
        c = MFMA16(wL1[mt][1], bf1, c);
        const int nb = w * 32 + mt * 16 + lq * 4;
        const f32x4 bq = *(const f32x4*)&bb[nb];
        const f32x4 wq = *(const f32x4*)&bb[256 + nb];
        const f16x4 ph = pre[nt][mt];
        f16x4 o;
#pragma unroll
        for (int q = 0; q < 4; ++q)
          o[q] = (_Float16)fmaxf(c[q] + (float)ph[q] + fmaf(s, wq[q], bq[q]), 0.f);
        *(f16x4*)(h1f + (w * 4 + nt) * 1024 + mt * 512 + lo1) = o;
      }
    }
    __syncthreads();

    // ========== layer 2: M=32, N=64, K=256  (+ next-step RNG fill) =======
    float enA[4], enB[4];
#pragma unroll
    for (int ntp = 0; ntp < 2; ++ntp) {
      f32x4 c[2][2];
#pragma unroll
      for (int mt = 0; mt < 2; ++mt)
#pragma unroll
        for (int ni = 0; ni < 2; ++ni)
          c[mt][ni] = (f32x4){0.f, 0.f, 0.f, 0.f};
#pragma unroll
      for (int half = 0; half < 2; ++half) {
        f16x8 bh[2][4];
#pragma unroll
        for (int ni = 0; ni < 2; ++ni)
#pragma unroll
          for (int k4 = 0; k4 < 4; ++k4)
            bh[ni][k4] = *(const f16x8*)
                (h1f + ((half * 4 + k4) * 4 + ntp * 2 + ni) * 1024 + rb);
#pragma unroll
        for (int mt = 0; mt < 2; ++mt)
#pragma unroll
          for (int k4 = 0; k4 < 4; ++k4) {
            const f16x8 aW = wL2[mt * 8 + half * 4 + k4];
            c[mt][0] = MFMA16(aW, bh[0][k4], c[mt][0]);
            c[mt][1] = MFMA16(aW, bh[1][k4], c[mt][1]);
          }
      }
      // next-step RNG draws interleave with this region's MFMA/LDS waits
      if (ntp == 0) {
#pragma unroll
        for (int q = 0; q < 4; ++q)
          enA[q] = bits_to_normal(draw_bits(kna, knb, giA + q));
      } else {
#pragma unroll
        for (int q = 0; q < 4; ++q)
          enB[q] = bits_to_normal(draw_bits(kna, knb, giB + q));
      }
#pragma unroll
      for (int mt = 0; mt < 2; ++mt) {
        const int nb = w * 32 + mt * 16 + lq * 4;
        const f32x4 bq = *(const f32x4*)&bb[512 + nb];
#pragma unroll
        for (int ni = 0; ni < 2; ++ni) {
          f16x4 o;
#pragma unroll
          for (int q = 0; q < 4; ++q)
            o[q] = (_Float16)fmaxf(c[mt][ni][q] + bq[q], 0.f);
          *(f16x4*)(h2f + (w * 4 + ntp * 2 + ni) * 1024 + mt * 512 + lo1) = o;
        }
      }
    }
    __syncthreads();

    // ========== layer 3 (dims [16*mt3,..+16)) + fused update ==========
    const f32x4 b3q = *(const f32x4*)&bb[768 + d0];
#pragma unroll
    for (int ni = 0; ni < 2; ++ni) {
      f32x4 dA = {0.f, 0.f, 0.f, 0.f}, dB = {0.f, 0.f, 0.f, 0.f};
#pragma unroll
      for (int half = 0; half < 2; ++half) {
        f16x8 bh[4];
#pragma unroll
        for (int k4 = 0; k4 < 4; ++k4)
          bh[k4] = *(const f16x8*)
              (h2f + ((half * 4 + k4) * 4 + ntb + ni) * 1024 + rb);
        dA = MFMA16(wL3[half * 4 + 0], bh[0], dA);
        dB = MFMA16(wL3[half * 4 + 1], bh[1], dB);
        dA = MFMA16(wL3[half * 4 + 2], bh[2], dA);
        dB = MFMA16(wL3[half * 4 + 3], bh[3], dB);
      }
      f16x4 hx;
#pragma unroll
      for (int q = 0; q < 4; ++q) {
        const float ov  = dA[q] + dB[q] + b3q[q];
        const float eta = ni ? etaB[q] : etaA[q];
        // nx = xv + ds*ov + P*(s*ov - xv + x0q) + sqrt(ds)*eta
        const float t1  = fmaf(s, ov, x0q[ni][q] - xv[ni][q]);
        float nx = fmaf(kSqrtDs, eta, xv[ni][q]);
        nx = fmaf(kDs, ov, nx);
        nx = fmaf(P, t1, nx);
        xv[ni][q] = nx;
        hx[q] = (_Float16)nx;
      }
      *(f16x4*)(xAf + (kt3 * 4 + ntb + ni) * 1024 + ln3) = hx;
    }
    // rotate RNG pipeline
#pragma unroll
    for (int q = 0; q < 4; ++q) { etaA[q] = enA[q]; etaB[q] = enB[q]; }
    __syncthreads();
  }

  // ---- write result (each lane owns its 8 elements) ----
#pragma unroll
  for (int ni = 0; ni < 2; ++ni) {
    const int row = (ntb + ni) * 16 + lm;
    const size_t ob = (size_t)samp * ((size_t)kObs * kDim) +
                      (size_t)(r0 + row) * kDim + d0;
    f32x4 v;
#pragma unroll
    for (int q = 0; q < 4; ++q) v[q] = xv[ni][q];
    *(f32x4*)(out + ob) = v;
  }
}

extern "C" void kernel_launch(void* const* d_in, const int* in_sizes, int n_in,
                              void* d_out, int out_size, void* d_ws, size_t ws_size,
                              hipStream_t stream) {
  const float* X0 = (const float*)d_in[0];
  const float* W1 = (const float*)d_in[1];
  const float* b1 = (const float*)d_in[2];
  const float* W2 = (const float*)d_in[3];
  const float* b2 = (const float*)d_in[4];
  const float* W3 = (const float*)d_in[5];
  const float* b3 = (const float*)d_in[6];
  _Float16* ws = (_Float16*)d_ws;   // 256 KB fragments + 2 KB key/scalar tables

  prep_weights<<<dim3(257), dim3(256), 0, stream>>>(W1, W2, W3, ws);
  sde_mfma<<<dim3(2048), dim3(512), 0, stream>>>(X0, W1, b1, b2, b3, ws,
                                                 (float*)d_out);
}